// Round 11
// baseline (49.435 us; speedup 1.0000x reference)
//
#include <hip/hip_runtime.h>
#include <hip/hip_bf16.h>

// Problem constants
#define BATCH 32768
#define NIN   256
#define NOUT  256
// degrees 1..8 via MFMA; degree 0 (T_0 = 1) folded into per-column bias

typedef __attribute__((ext_vector_type(8))) short bf16x8;
typedef __attribute__((ext_vector_type(4))) float f32x4;
typedef __attribute__((ext_vector_type(2))) float f32x2;
typedef __attribute__((ext_vector_type(4))) unsigned int u32x4;

static __device__ __forceinline__ unsigned short bf16_rne(float f) {
  unsigned u = __float_as_uint(f);
  u += 0x7fffu + ((u >> 16) & 1u);
  return (unsigned short)(u >> 16);
}

// fast tanh: t = sign(v) * (1 - z) / (1 + z), z = exp(-2|v|)
static __device__ __forceinline__ float fast_tanh(float v) {
  float a = fabsf(v);
  float z = __expf(-2.0f * a);
  float r = (1.0f - z) * __builtin_amdgcn_rcpf(1.0f + z);
  return copysignf(r, v);
}

static __device__ __forceinline__ unsigned pack_pair(f32x2 v) {
  __hip_bfloat162 h2 = __float22bfloat162_rn(make_float2(v[0], v[1]));
  union { __hip_bfloat162 h; unsigned u; } cv;
  cv.h = h2;
  return cv.u;
}

static __device__ __forceinline__ void init_state(const f32x4 x0, const f32x4 x1,
                                                  f32x2* cur, f32x2* prev,
                                                  f32x2* t2) {
  #pragma unroll
  for (int p = 0; p < 4; ++p) {
    float va = (p < 2) ? x0[2 * p]     : x1[2 * p - 4];
    float vb = (p < 2) ? x0[2 * p + 1] : x1[2 * p - 3];
    float ta = fast_tanh(va);
    float tb = fast_tanh(vb);
    cur[p]  = (f32x2){ta, tb};        // T_1
    t2[p]   = cur[p] + cur[p];
    prev[p] = (f32x2){1.0f, 1.0f};    // T_0
  }
}

// ---------------------------------------------------------------------------
// Prepack: Bp[((dm*8+ic)*16+tile)*512 + kg*128 + col*8 + j] =
//          bf16( c_basis[n][i][dm+1] * c_act[n][i] )
//   with i = ic*32 + kg*8 + j,  n = tile*16 + col.
// ---------------------------------------------------------------------------
__global__ void cheby_prepack(const float* __restrict__ cb,
                              const float* __restrict__ ca,
                              unsigned short* __restrict__ Bp) {
  int tid = blockIdx.x * 256 + threadIdx.x;
  int j    = tid & 7;
  int col  = (tid >> 3) & 15;
  int kg   = (tid >> 7) & 3;
  int tile = (tid >> 9) & 15;
  int ic   = (tid >> 13) & 7;
  int dm   = tid >> 16;           // d-1, 0..7
  int i = ic * 32 + kg * 8 + j;
  int n = tile * 16 + col;
  float w = cb[n * (NIN * 9) + i * 9 + (dm + 1)] * ca[n * NIN + i];
  Bp[tid] = bf16_rne(w);
}

// bias[n] = sum_i c_basis[n][i][0] * c_act[n][i]   (T_0 == 1 term)
__global__ void cheby_bias(const float* __restrict__ cb,
                           const float* __restrict__ ca,
                           float* __restrict__ bias) {
  int n = blockIdx.x;
  int l = threadIdx.x;            // 64 threads = one wave
  float s = 0.0f;
  #pragma unroll
  for (int k = 0; k < 4; ++k) {
    int i = l + k * 64;
    s += cb[n * (NIN * 9) + i * 9] * ca[n * NIN + i];
  }
  #pragma unroll
  for (int off = 32; off; off >>= 1) s += __shfl_down(s, off);
  if (l == 0) bias[n] = s;
}

// ---------------------------------------------------------------------------
// Fused cheby + GEMM, 2-degree phases (32 MFMA per barrier).
// Grid: 256 blocks x 512 threads (8 waves), 1 block/CU, LDS 128KB.
// Block tile: 128 rows x 256 cols; wave tile 64x64 (wr=w>>2, wc=w&3).
// Per phase (4 phases per ic, 32 total):
//   { 8x ds_read A frags (THIS phase; complete during barrier crossing) ||
//     8x B-frag loads (NEXT phase, counted vmcnt at use) ||
//     2 basis degree-slices of ic+1 -> ds_write buf^1 }
//   -> s_barrier -> lgkmcnt(0) -> 32 MFMA (dd outer: acc reuse dist = 16).
// Halves the per-barrier fixed overhead vs 1-degree phases (R10's binder).
// ---------------------------------------------------------------------------
__global__ __launch_bounds__(512, 2)
void cheby_mfma(const float* __restrict__ x,
                const unsigned short* __restrict__ Bp,
                const float* __restrict__ bias,
                float* __restrict__ out) {
  // [buf][d-1][plane 0..7][frag: kg*256B + row16*16B] -- 1KB planes, 128KB
  __shared__ unsigned short Asm[2][8][8][512];

  int tid  = threadIdx.x;
  int w    = tid >> 6;            // 0..7
  int lane = tid & 63;
  int row16 = lane & 15;          // A row / B col / C-D col
  int kg    = lane >> 4;          // k-group 0..3

  int wr = w >> 2;                // row half (0..1)
  int wc = w & 3;                 // col strip (0..3)
  int base_row = blockIdx.x * 128;
  int tile0    = wc * 4;          // wave's 4 column tiles (64 cols)

  // writer role: wave w covers rows w*16..w*16+15 (plane w)
  const float* xw = x + (size_t)(base_row + w * 16 + row16) * NIN + kg * 8;
  char* wbase = (char*)Asm + (w * 1024 + lane * 16);   // + d*8192 + buf*65536
  // reader
  const char* abase   = (const char*)Asm + lane * 16;
  const char* bp_lane = (const char*)Bp + kg * 256 + row16 * 16;

  f32x4 acc[4][4];
  #pragma unroll
  for (int a = 0; a < 4; ++a)
    #pragma unroll
    for (int b = 0; b < 4; ++b) acc[a][b] = (f32x4)0.0f;

  // ---- prologue: full basis(0) -> buf0 ----
  f32x4 xa = *(const f32x4*)xw;
  f32x4 xb = *(const f32x4*)(xw + 4);
  {
    f32x2 c0[4], p0[4], t0[4];
    init_state(xa, xb, c0, p0, t0);
    #pragma unroll
    for (int d = 1; d <= 8; ++d) {
      u32x4 pk;
      #pragma unroll
      for (int q = 0; q < 4; ++q) pk[q] = pack_pair(c0[q]);
      *(u32x4*)(wbase + (d - 1) * 8192) = pk;
      if (d < 8) {
        #pragma unroll
        for (int q = 0; q < 4; ++q) {
          f32x2 nx = __builtin_elementwise_fma(t0[q], c0[q], -p0[q]);
          p0[q] = c0[q];
          c0[q] = nx;
        }
      }
    }
  }
  // x(1) + recurrence state for basis(1)
  xa = *(const f32x4*)(xw + 32);
  xb = *(const f32x4*)(xw + 36);
  f32x2 cur[4], prev[4], t2[4];
  init_state(xa, xb, cur, prev, t2);

  // B double buffer: [parity][dd][nt]; load degrees 0,1 of ic=0
  bf16x8 bfr[2][2][4];
  {
    const char* bp0 = bp_lane + (size_t)tile0 * 1024;
    #pragma unroll
    for (int dd = 0; dd < 2; ++dd)
      #pragma unroll
      for (int nt = 0; nt < 4; ++nt)
        bfr[0][dd][nt] =
            *(const bf16x8*)(bp0 + (size_t)dd * 131072 + nt * 1024);
  }
  // make basis(0) visible to all waves
  __builtin_amdgcn_sched_barrier(0);
  asm volatile("s_waitcnt lgkmcnt(0)" ::: "memory");
  __builtin_amdgcn_s_barrier();
  __builtin_amdgcn_sched_barrier(0);

  // ---- main loop: ic = 0..6, 4 phases each (2 degrees per phase) ----
  for (int ic = 0; ic < 7; ++ic) {
    const char* ai   = abase + (ic & 1) * 65536 + (wr * 4) * 1024;
    char*       wp   = wbase + ((ic + 1) & 1) * 65536;
    const char* bpi  = bp_lane + (size_t)(ic * 16 + tile0) * 1024;
    const char* bpin = bp_lane + (size_t)((ic + 1) * 16 + tile0) * 1024;

    #pragma unroll
    for (int ph = 0; ph < 4; ++ph) {
      const int d0 = ph * 2;               // degrees d0, d0+1 (dm index)
      // A frags for THIS phase (complete during barrier crossing)
      bf16x8 af[2][4];
      #pragma unroll
      for (int dd = 0; dd < 2; ++dd)
        #pragma unroll
        for (int mt = 0; mt < 4; ++mt)
          af[dd][mt] =
              *(const bf16x8*)(ai + (d0 + dd) * 8192 + mt * 1024);
      // B frags for NEXT phase (1 phase deep, counted vmcnt at use)
      if (ph < 3) {
        #pragma unroll
        for (int dd = 0; dd < 2; ++dd)
          #pragma unroll
          for (int nt = 0; nt < 4; ++nt)
            bfr[(ph + 1) & 1][dd][nt] = *(const bf16x8*)(
                bpi + (size_t)(d0 + 2 + dd) * 131072 + nt * 1024);
      } else {
        #pragma unroll
        for (int dd = 0; dd < 2; ++dd)
          #pragma unroll
          for (int nt = 0; nt < 4; ++nt)
            bfr[0][dd][nt] = *(const bf16x8*)(
                bpin + (size_t)dd * 131072 + nt * 1024);
      }
      // basis: two degree-slices of ic+1 (write T_{d0+1}, T_{d0+2})
      #pragma unroll
      for (int s = 0; s < 2; ++s) {
        u32x4 pk;
        #pragma unroll
        for (int q = 0; q < 4; ++q) pk[q] = pack_pair(cur[q]);
        *(u32x4*)(wp + (d0 + s) * 8192) = pk;
        if (d0 + s < 7) {
          #pragma unroll
          for (int q = 0; q < 4; ++q) {
            f32x2 nx = __builtin_elementwise_fma(t2[q], cur[q], -prev[q]);
            prev[q] = cur[q];
            cur[q]  = nx;
          }
        }
      }
      if (ph == 1 && ic <= 5) {            // x for ic+2
        xa = *(const f32x4*)(xw + (ic + 2) * 32);
        xb = *(const f32x4*)(xw + (ic + 2) * 32 + 4);
      }
      if (ph == 3 && ic <= 5)              // state for basis(ic+2)
        init_state(xa, xb, cur, prev, t2);

      // barrier, then wait this phase's A reads (landed during crossing)
      __builtin_amdgcn_sched_barrier(0);
      __builtin_amdgcn_s_barrier();
      asm volatile("s_waitcnt lgkmcnt(0)" ::: "memory");
      __builtin_amdgcn_sched_barrier(0);

      __builtin_amdgcn_s_setprio(1);
      #pragma unroll
      for (int dd = 0; dd < 2; ++dd)
        #pragma unroll
        for (int mt = 0; mt < 4; ++mt)
          #pragma unroll
          for (int nt = 0; nt < 4; ++nt)
            acc[mt][nt] = __builtin_amdgcn_mfma_f32_16x16x32_bf16(
                af[dd][mt], bfr[ph & 1][dd][nt], acc[mt][nt], 0, 0, 0);
      __builtin_amdgcn_s_setprio(0);
    }
  }

  // ---- final ic = 7: no basis work, no barriers ----
  {
    const char* ai  = abase + 65536 + (wr * 4) * 1024;   // buf1
    const char* bpi = bp_lane + (size_t)(7 * 16 + tile0) * 1024;
    #pragma unroll
    for (int ph = 0; ph < 4; ++ph) {
      const int d0 = ph * 2;
      bf16x8 af[2][4];
      #pragma unroll
      for (int dd = 0; dd < 2; ++dd)
        #pragma unroll
        for (int mt = 0; mt < 4; ++mt)
          af[dd][mt] =
              *(const bf16x8*)(ai + (d0 + dd) * 8192 + mt * 1024);
      if (ph < 3) {
        #pragma unroll
        for (int dd = 0; dd < 2; ++dd)
          #pragma unroll
          for (int nt = 0; nt < 4; ++nt)
            bfr[(ph + 1) & 1][dd][nt] = *(const bf16x8*)(
                bpi + (size_t)(d0 + 2 + dd) * 131072 + nt * 1024);
      }
      __builtin_amdgcn_s_setprio(1);
      #pragma unroll
      for (int dd = 0; dd < 2; ++dd)
        #pragma unroll
        for (int mt = 0; mt < 4; ++mt)
          #pragma unroll
          for (int nt = 0; nt < 4; ++nt)
            acc[mt][nt] = __builtin_amdgcn_mfma_f32_16x16x32_bf16(
                af[dd][mt], bfr[ph & 1][dd][nt], acc[mt][nt], 0, 0, 0);
      __builtin_amdgcn_s_setprio(0);
    }
  }

  // epilogue: C/D layout col = lane&15, row = (lane>>4)*4 + q  (m89/m91)
  #pragma unroll
  for (int nt = 0; nt < 4; ++nt) {
    int c = (tile0 + nt) * 16 + row16;
    float bv = bias[c];
    #pragma unroll
    for (int mt = 0; mt < 4; ++mt) {
      int r0 = base_row + wr * 64 + mt * 16 + kg * 4;
      #pragma unroll
      for (int q = 0; q < 4; ++q)
        out[(size_t)(r0 + q) * NOUT + c] = acc[mt][nt][q] + bv;
    }
  }
}

extern "C" void kernel_launch(void* const* d_in, const int* in_sizes, int n_in,
                              void* d_out, int out_size, void* d_ws, size_t ws_size,
                              hipStream_t stream) {
  const float* x  = (const float*)d_in[0];
  const float* cb = (const float*)d_in[1];   // c_basis (256,256,9)
  const float* ca = (const float*)d_in[2];   // c_act   (256,256)
  float* out = (float*)d_out;

  unsigned short* Bp = (unsigned short*)d_ws;                    // 1 MB
  float* bias = (float*)((char*)d_ws + 8 * NIN * NOUT * 2);      // 1 KB

  cheby_prepack<<<(8 * NIN * NOUT) / 256, 256, 0, stream>>>(cb, ca, Bp);
  cheby_bias<<<NOUT, 64, 0, stream>>>(cb, ca, bias);
  cheby_mfma<<<256, 512, 0, stream>>>(x, Bp, bias, out);
}